// Round 4
// baseline (1111.863 us; speedup 1.0000x reference)
//
#include <hip/hip_runtime.h>
#include <hip/hip_bf16.h>

typedef unsigned short u16;
typedef unsigned int u32;
typedef unsigned long long u64;
typedef __attribute__((ext_vector_type(8))) short short8;
typedef __attribute__((ext_vector_type(4))) float float4v;

#define B_DIM 64
#define H_DIM 2048
#define K_DIM 256
#define GRID  1024
#define NTHR  256

// workspace layout (bytes)
#define WS_WBF   0ull                         // 2048*2048*2 = 8388608
#define WS_AQ    (8388608ull)                 // 128*2048*2  = 524288
#define WS_Q     (WS_AQ + 524288ull)          // 64*2048*4   = 524288
#define WS_KN2   (WS_Q + 524288ull)           // 16384*4
#define WS_DOTS  (WS_KN2 + 65536ull)          // 16384*4
#define WS_ATTN  (WS_DOTS + 65536ull)         // 16384*4
#define WS_KBF   (WS_ATTN + 65536ull)         // 16384*2048*2 = 67108864
#define WS_BAR   (WS_KBF + 67108864ull)       // 4 u32 barrier counters

__device__ __forceinline__ u16 f2bf(float f) {
    unsigned int u = __float_as_uint(f);
    unsigned int r = (u + 0x7fffu + ((u >> 16) & 1u)) >> 16;
    return (u16)r;
}

__device__ __forceinline__ u64 pack4(float4v v) {
    u64 a0 = f2bf(v.x), a1 = f2bf(v.y), a2 = f2bf(v.z), a3 = f2bf(v.w);
    return a0 | (a1 << 16) | (a2 << 32) | (a3 << 48);
}

// async global->LDS 16B/lane; lds dest = wave-uniform base + lane*16
__device__ __forceinline__ void llds16(const u16* g, u16* l) {
    __builtin_amdgcn_global_load_lds(
        (__attribute__((address_space(1))) void*)g,
        (__attribute__((address_space(3))) void*)l, 16, 0, 0);
}

// device-scope grid barrier (all GRID blocks co-resident by construction)
__device__ __forceinline__ void gbar(u32* bar, u32 n) {
    __syncthreads();
    if (threadIdx.x == 0) {
        __hip_atomic_fetch_add(bar, 1u, __ATOMIC_ACQ_REL, __HIP_MEMORY_SCOPE_AGENT);
        while (__hip_atomic_load(bar, __ATOMIC_ACQUIRE, __HIP_MEMORY_SCOPE_AGENT) < n)
            __builtin_amdgcn_s_sleep(2);
    }
    __syncthreads();
}

// ---- GEMM tile helpers (XOR-swizzled LDS: granule g of row r at slot g^((r>>1)&3)) ----
__device__ __forceinline__ void gemm0_tile(const u16* __restrict__ Aq, const u16* __restrict__ Wb,
                                           float* __restrict__ qout, u16* As, u16* Bs,
                                           int nt, int ksplit) {
    const int tid = threadIdx.x;
    const int wave = tid >> 6, lane = tid & 63;
    const int l15 = lane & 15, qd = lane >> 4;
    const int wm = wave >> 1, wn = wave & 1;
    const int n0 = nt * 128;
    const int grow = lane >> 2;
    const int gcol = (((lane & 3) ^ ((lane >> 3) & 3)) * 8);
    const int sw = (l15 >> 1) & 3;
    float4v acc[4][4] = {};
    const int kb0 = ksplit * 512;
    for (int kk = 0; kk < 16; ++kk) {
        const int k0 = kb0 + kk * 32;
        #pragma unroll
        for (int i = 0; i < 2; ++i) {
            const int r = wave * 32 + i * 16;
            llds16(Wb + (size_t)(n0 + r + grow) * H_DIM + k0 + gcol, &Bs[r * 32]);
            llds16(Aq + (size_t)(r + grow) * H_DIM + k0 + gcol, &As[r * 32]);
        }
        __syncthreads();
        short8 af[4], bf_[4];
        #pragma unroll
        for (int mi = 0; mi < 4; ++mi)
            af[mi] = *(const short8*)&As[(wm * 64 + mi * 16 + l15) * 32 + ((qd ^ sw) * 8)];
        #pragma unroll
        for (int ni = 0; ni < 4; ++ni)
            bf_[ni] = *(const short8*)&Bs[(wn * 64 + ni * 16 + l15) * 32 + ((qd ^ sw) * 8)];
        #pragma unroll
        for (int mi = 0; mi < 4; ++mi)
            #pragma unroll
            for (int ni = 0; ni < 4; ++ni)
                acc[mi][ni] = __builtin_amdgcn_mfma_f32_16x16x32_bf16(af[mi], bf_[ni], acc[mi][ni], 0, 0, 0);
        __syncthreads();
    }
    const int n0w = n0 + wn * 64;
    if (wm == 0) {
        #pragma unroll
        for (int mi = 0; mi < 4; ++mi)
            #pragma unroll
            for (int reg = 0; reg < 4; ++reg) {
                const int m = mi * 16 + qd * 4 + reg;   // 0..63 == b
                #pragma unroll
                for (int ni = 0; ni < 4; ++ni)
                    atomicAdd(&qout[m * H_DIM + n0w + ni * 16 + l15], acc[mi][ni][reg]);
            }
    }
}

__device__ __forceinline__ void gemmC_tile(const u16* __restrict__ Kbf, const u16* __restrict__ Wb,
                                           const float* __restrict__ bias, const float* __restrict__ q,
                                           float* __restrict__ kn2, float* __restrict__ dots,
                                           u16* As, u16* Bs, int x) {
    const int tid = threadIdx.x;
    const int wave = tid >> 6, lane = tid & 63;
    const int l15 = lane & 15, qd = lane >> 4;
    const int wm = wave >> 1, wn = wave & 1;
    const int mt = (x >> 6) * 4 + (x & 3);     // L2-locality swizzle: 4 mt x 16 nt groups
    const int nt = (x >> 2) & 15;
    const int m0 = mt * 128, n0 = nt * 128;
    const int grow = lane >> 2;
    const int gcol = (((lane & 3) ^ ((lane >> 3) & 3)) * 8);
    const int sw = (l15 >> 1) & 3;
    float4v acc[4][4] = {};
    for (int kk = 0; kk < 64; ++kk) {
        const int k0 = kk * 32;
        #pragma unroll
        for (int i = 0; i < 2; ++i) {
            const int r = wave * 32 + i * 16;
            llds16(Wb + (size_t)(n0 + r + grow) * H_DIM + k0 + gcol, &Bs[r * 32]);
            llds16(Kbf + (size_t)(m0 + r + grow) * H_DIM + k0 + gcol, &As[r * 32]);
        }
        __syncthreads();
        short8 af[4], bf_[4];
        #pragma unroll
        for (int mi = 0; mi < 4; ++mi)
            af[mi] = *(const short8*)&As[(wm * 64 + mi * 16 + l15) * 32 + ((qd ^ sw) * 8)];
        #pragma unroll
        for (int ni = 0; ni < 4; ++ni)
            bf_[ni] = *(const short8*)&Bs[(wn * 64 + ni * 16 + l15) * 32 + ((qd ^ sw) * 8)];
        #pragma unroll
        for (int mi = 0; mi < 4; ++mi)
            #pragma unroll
            for (int ni = 0; ni < 4; ++ni)
                acc[mi][ni] = __builtin_amdgcn_mfma_f32_16x16x32_bf16(af[mi], bf_[ni], acc[mi][ni], 0, 0, 0);
        __syncthreads();
    }
    const int n0w = n0 + wn * 64;
    float bv[4];
    #pragma unroll
    for (int ni = 0; ni < 4; ++ni) bv[ni] = bias[n0w + ni * 16 + l15];
    #pragma unroll
    for (int mi = 0; mi < 4; ++mi)
        #pragma unroll
        for (int reg = 0; reg < 4; ++reg) {
            const int mloc = mi * 16 + qd * 4 + reg;     // b index
            const int mg = m0 + wm * 64 + mloc;
            const float* qrow = q + mloc * H_DIM;
            float s2 = 0.f, sd = 0.f;
            #pragma unroll
            for (int ni = 0; ni < 4; ++ni) {
                const float y = acc[mi][ni][reg] + bv[ni];
                const float qv = qrow[n0w + ni * 16 + l15];
                s2 += y * y; sd += y * qv;
            }
            #pragma unroll
            for (int off = 1; off < 16; off <<= 1) {
                s2 += __shfl_xor(s2, off);
                sd += __shfl_xor(sd, off);
            }
            if (l15 == 0) {
                atomicAdd(&kn2[mg], s2);
                atomicAdd(&dots[mg], sd);
            }
        }
}

// ---------------- single fused persistent kernel ----------------
__global__ __launch_bounds__(256, 4) void fused_kernel(
        const float* __restrict__ input, const float* __restrict__ kb,
        const float* __restrict__ W, const float* __restrict__ bias,
        float* __restrict__ out, char* __restrict__ ws) {
    __shared__ __align__(16) u16 As[128 * 32];
    __shared__ __align__(16) u16 Bs[128 * 32];

    u16*   Wb   = (u16*)(ws + WS_WBF);
    u16*   Aq   = (u16*)(ws + WS_AQ);
    float* q    = (float*)(ws + WS_Q);
    float* kn2  = (float*)(ws + WS_KN2);
    float* dots = (float*)(ws + WS_DOTS);
    float* attn = (float*)(ws + WS_ATTN);
    u16*   Kbf  = (u16*)(ws + WS_KBF);
    u32*   bar  = (u32*)(ws + WS_BAR);

    const int tid = threadIdx.x;
    const int bid = blockIdx.x;
    const int gid = bid * NTHR + tid;          // 0..262143

    // ---- Phase A: W->bf16, input->Aq, q=bias, zero kn2/dots, out=input ----
    {
        const float4v* w4 = (const float4v*)W;
        u64* wd = (u64*)Wb;
        #pragma unroll
        for (int i = 0; i < 4; ++i) {
            const int idx = gid + i * (GRID * NTHR);
            wd[idx] = pack4(w4[idx]);
        }
        if (gid < 65536) {
            u64 v = 0;
            if (gid < 32768) v = pack4(((const float4v*)input)[gid]);
            ((u64*)Aq)[gid] = v;
        }
        if (gid < 32768)
            ((float4v*)q)[gid] = ((const float4v*)bias)[gid & 511];
        if (gid < 4096) ((float4v*)kn2)[gid] = float4v{0.f, 0.f, 0.f, 0.f};
        else if (gid < 8192) ((float4v*)dots)[gid - 4096] = float4v{0.f, 0.f, 0.f, 0.f};
        if (gid >= 8192 && gid < 8192 + 32768) {
            const int t = gid - 8192;
            ((float4v*)out)[t] = ((const float4v*)input)[t];
        }
    }
    gbar(bar + 0, GRID);

    // ---- Phase B: blocks 0-63 gemm0 (q += in@W^T) ; blocks 64+ convert kb->bf16 ----
    if (bid < 64) {
        gemm0_tile(Aq, Wb, q, As, Bs, bid & 15, bid >> 4);
    } else {
        const float4v* s4 = (const float4v*)kb;
        u64* d8 = (u64*)Kbf;
        for (int i = (bid - 64) * NTHR + tid; i < 8388608; i += (GRID - 64) * NTHR)
            d8[i] = pack4(s4[i]);
    }
    gbar(bar + 1, GRID);

    // ---- Phase C: big GEMM, 2048 tiles, fused norm/dot epilogue ----
    for (int x = bid; x < 2048; x += GRID)
        gemmC_tile(Kbf, Wb, bias, q, kn2, dots, As, Bs, x);
    gbar(bar + 2, GRID);

    // ---- Phase D: softmax over K per b (blocks 0-63) ----
    if (bid < 64) {
        float* buf = (float*)As;
        const int b = bid;
        float s = 0.f;
        #pragma unroll
        for (int i = 0; i < 8; ++i) {
            float v = q[b * H_DIM + i * 256 + tid];
            s += v * v;
        }
        // block reduce sum
        #pragma unroll
        for (int o = 32; o >= 1; o >>= 1) s += __shfl_xor(s, o);
        if ((tid & 63) == 0) buf[tid >> 6] = s;
        __syncthreads();
        const float qn = fmaxf(sqrtf(buf[0] + buf[1] + buf[2] + buf[3]), 1e-8f);
        __syncthreads();
        const int k = tid;
        const float kn = fmaxf(sqrtf(kn2[k * B_DIM + b]), 1e-8f);
        const float sc = dots[k * B_DIM + b] / (qn * kn);
        float mx = sc;
        #pragma unroll
        for (int o = 32; o >= 1; o >>= 1) mx = fmaxf(mx, __shfl_xor(mx, o));
        if ((tid & 63) == 0) buf[tid >> 6] = mx;
        __syncthreads();
        mx = fmaxf(fmaxf(buf[0], buf[1]), fmaxf(buf[2], buf[3]));
        __syncthreads();
        const float e = expf(sc - mx);
        float se = e;
        #pragma unroll
        for (int o = 32; o >= 1; o >>= 1) se += __shfl_xor(se, o);
        if ((tid & 63) == 0) buf[tid >> 6] = se;
        __syncthreads();
        se = buf[0] + buf[1] + buf[2] + buf[3];
        attn[k * B_DIM + b] = e / se;
    }
    gbar(bar + 3, GRID);

    // ---- Phase E: out += sum_k attn[k,b]*kb[k,b,:], split-K over 4 chunks (atomics) ----
    if (bid < 512) {
        const int kc = bid >> 7;                 // 0..3
        const int b  = (bid & 127) >> 1;         // 0..63
        const int h4 = (bid & 1) * 256 + tid;    // 0..511 (float4 unit)
        float* a_s = (float*)Bs;
        if (tid < 64) a_s[tid] = attn[(kc * 64 + tid) * B_DIM + b];
        __syncthreads();
        const u32* base = (const u32*)Kbf;
        float s0 = 0.f, s1 = 0.f, s2 = 0.f, s3 = 0.f;
        #pragma unroll 8
        for (int i = 0; i < 64; ++i) {
            const int k = kc * 64 + i;
            const size_t off = (((size_t)(k * B_DIM + b) * H_DIM) >> 1) + h4 * 2;
            const u32 p0 = base[off], p1 = base[off + 1];
            const float a = a_s[i];
            s0 += a * __uint_as_float(p0 << 16);
            s1 += a * __uint_as_float(p0 & 0xffff0000u);
            s2 += a * __uint_as_float(p1 << 16);
            s3 += a * __uint_as_float(p1 & 0xffff0000u);
        }
        float* o = out + (size_t)b * H_DIM + h4 * 4;
        atomicAdd(o + 0, s0); atomicAdd(o + 1, s1);
        atomicAdd(o + 2, s2); atomicAdd(o + 3, s3);
    }
}

extern "C" void kernel_launch(void* const* d_in, const int* in_sizes, int n_in,
                              void* d_out, int out_size, void* d_ws, size_t ws_size,
                              hipStream_t stream) {
    const float* input = (const float*)d_in[0];
    const float* kb    = (const float*)d_in[1];
    const float* W     = (const float*)d_in[2];
    const float* bias  = (const float*)d_in[3];
    float* out = (float*)d_out;
    char* ws = (char*)d_ws;

    hipMemsetAsync(ws + WS_BAR, 0, 64, stream);
    fused_kernel<<<GRID, NTHR, 0, stream>>>(input, kb, W, bias, out, ws);
}

// Round 5
// 703.327 us; speedup vs baseline: 1.5809x; 1.5809x over previous
//
#include <hip/hip_runtime.h>
#include <hip/hip_bf16.h>

typedef unsigned short u16;
typedef unsigned int u32;
typedef unsigned long long u64;
typedef __attribute__((ext_vector_type(8))) short short8;
typedef __attribute__((ext_vector_type(4))) float float4v;

#define B_DIM 64
#define H_DIM 2048
#define K_DIM 256
#define GRID  1024
#define NTHR  256

// workspace layout (bytes)
#define WS_WBF   0ull                         // 2048*2048*2 = 8388608
#define WS_AQ    (8388608ull)                 // 128*2048*2  = 524288
#define WS_Q     (WS_AQ + 524288ull)          // 64*2048*4   = 524288
#define WS_KN2   (WS_Q + 524288ull)           // 16384*4
#define WS_DOTS  (WS_KN2 + 65536ull)          // 16384*4
#define WS_KBF   (WS_DOTS + 65536ull)         // 16384*2048*2 = 67108864
#define WS_BAR   (WS_KBF + 67108864ull)       // barrier counters

__device__ __forceinline__ u16 f2bf(float f) {
    unsigned int u = __float_as_uint(f);
    unsigned int r = (u + 0x7fffu + ((u >> 16) & 1u)) >> 16;
    return (u16)r;
}

__device__ __forceinline__ u64 pack4(float4v v) {
    u64 a0 = f2bf(v.x), a1 = f2bf(v.y), a2 = f2bf(v.z), a3 = f2bf(v.w);
    return a0 | (a1 << 16) | (a2 << 32) | (a3 << 48);
}

// async global->LDS 16B/lane; lds dest = wave-uniform base + lane*16
__device__ __forceinline__ void llds16(const u16* g, u16* l) {
    __builtin_amdgcn_global_load_lds(
        (__attribute__((address_space(1))) void*)g,
        (__attribute__((address_space(3))) void*)l, 16, 0, 0);
}

// device-scope grid barrier. Release once, spin RELAXED (no per-iter cache
// invalidate!), single acquire at exit. s_sleep(32) backoff keeps the L3
// line traffic negligible.
__device__ __forceinline__ void gbar(u32* bar, u32 n) {
    __syncthreads();
    if (threadIdx.x == 0) {
        __hip_atomic_fetch_add(bar, 1u, __ATOMIC_RELEASE, __HIP_MEMORY_SCOPE_AGENT);
        while (__hip_atomic_load(bar, __ATOMIC_RELAXED, __HIP_MEMORY_SCOPE_AGENT) < n)
            __builtin_amdgcn_s_sleep(32);
        (void)__hip_atomic_load(bar, __ATOMIC_ACQUIRE, __HIP_MEMORY_SCOPE_AGENT);
    }
    __syncthreads();
}

// ---- GEMM tile helpers (XOR-swizzled LDS: granule g of row r at slot g^((r>>1)&3)) ----
__device__ __forceinline__ void gemm0_tile(const u16* __restrict__ Aq, const u16* __restrict__ Wb,
                                           float* __restrict__ qout, u16* As, u16* Bs,
                                           int nt, int ksplit) {
    const int tid = threadIdx.x;
    const int wave = tid >> 6, lane = tid & 63;
    const int l15 = lane & 15, qd = lane >> 4;
    const int wm = wave >> 1, wn = wave & 1;
    const int n0 = nt * 128;
    const int grow = lane >> 2;
    const int gcol = (((lane & 3) ^ ((lane >> 3) & 3)) * 8);
    const int sw = (l15 >> 1) & 3;
    float4v acc[4][4] = {};
    const int kb0 = ksplit * 512;
    for (int kk = 0; kk < 16; ++kk) {
        const int k0 = kb0 + kk * 32;
        #pragma unroll
        for (int i = 0; i < 2; ++i) {
            const int r = wave * 32 + i * 16;
            llds16(Wb + (size_t)(n0 + r + grow) * H_DIM + k0 + gcol, &Bs[r * 32]);
            llds16(Aq + (size_t)(r + grow) * H_DIM + k0 + gcol, &As[r * 32]);
        }
        __syncthreads();
        short8 af[4], bf_[4];
        #pragma unroll
        for (int mi = 0; mi < 4; ++mi)
            af[mi] = *(const short8*)&As[(wm * 64 + mi * 16 + l15) * 32 + ((qd ^ sw) * 8)];
        #pragma unroll
        for (int ni = 0; ni < 4; ++ni)
            bf_[ni] = *(const short8*)&Bs[(wn * 64 + ni * 16 + l15) * 32 + ((qd ^ sw) * 8)];
        #pragma unroll
        for (int mi = 0; mi < 4; ++mi)
            #pragma unroll
            for (int ni = 0; ni < 4; ++ni)
                acc[mi][ni] = __builtin_amdgcn_mfma_f32_16x16x32_bf16(af[mi], bf_[ni], acc[mi][ni], 0, 0, 0);
        __syncthreads();
    }
    const int n0w = n0 + wn * 64;
    if (wm == 0) {
        #pragma unroll
        for (int mi = 0; mi < 4; ++mi)
            #pragma unroll
            for (int reg = 0; reg < 4; ++reg) {
                const int m = mi * 16 + qd * 4 + reg;   // 0..63 == b
                #pragma unroll
                for (int ni = 0; ni < 4; ++ni)
                    atomicAdd(&qout[m * H_DIM + n0w + ni * 16 + l15], acc[mi][ni][reg]);
            }
    }
}

__device__ __forceinline__ void gemmC_tile(const u16* __restrict__ Kbf, const u16* __restrict__ Wb,
                                           const float* __restrict__ bias, const float* __restrict__ q,
                                           float* __restrict__ kn2, float* __restrict__ dots,
                                           u16* As, u16* Bs, int x) {
    const int tid = threadIdx.x;
    const int wave = tid >> 6, lane = tid & 63;
    const int l15 = lane & 15, qd = lane >> 4;
    const int wm = wave >> 1, wn = wave & 1;
    const int mt = (x >> 6) * 4 + (x & 3);     // L2-locality swizzle: 4 mt x 16 nt groups
    const int nt = (x >> 2) & 15;
    const int m0 = mt * 128, n0 = nt * 128;
    const int grow = lane >> 2;
    const int gcol = (((lane & 3) ^ ((lane >> 3) & 3)) * 8);
    const int sw = (l15 >> 1) & 3;
    float4v acc[4][4] = {};
    for (int kk = 0; kk < 64; ++kk) {
        const int k0 = kk * 32;
        #pragma unroll
        for (int i = 0; i < 2; ++i) {
            const int r = wave * 32 + i * 16;
            llds16(Wb + (size_t)(n0 + r + grow) * H_DIM + k0 + gcol, &Bs[r * 32]);
            llds16(Kbf + (size_t)(m0 + r + grow) * H_DIM + k0 + gcol, &As[r * 32]);
        }
        __syncthreads();
        short8 af[4], bf_[4];
        #pragma unroll
        for (int mi = 0; mi < 4; ++mi)
            af[mi] = *(const short8*)&As[(wm * 64 + mi * 16 + l15) * 32 + ((qd ^ sw) * 8)];
        #pragma unroll
        for (int ni = 0; ni < 4; ++ni)
            bf_[ni] = *(const short8*)&Bs[(wn * 64 + ni * 16 + l15) * 32 + ((qd ^ sw) * 8)];
        #pragma unroll
        for (int mi = 0; mi < 4; ++mi)
            #pragma unroll
            for (int ni = 0; ni < 4; ++ni)
                acc[mi][ni] = __builtin_amdgcn_mfma_f32_16x16x32_bf16(af[mi], bf_[ni], acc[mi][ni], 0, 0, 0);
        __syncthreads();
    }
    const int n0w = n0 + wn * 64;
    float bv[4];
    #pragma unroll
    for (int ni = 0; ni < 4; ++ni) bv[ni] = bias[n0w + ni * 16 + l15];
    #pragma unroll
    for (int mi = 0; mi < 4; ++mi)
        #pragma unroll
        for (int reg = 0; reg < 4; ++reg) {
            const int mloc = mi * 16 + qd * 4 + reg;     // b index
            const int mg = m0 + wm * 64 + mloc;
            const float* qrow = q + mloc * H_DIM;
            float s2 = 0.f, sd = 0.f;
            #pragma unroll
            for (int ni = 0; ni < 4; ++ni) {
                const float y = acc[mi][ni][reg] + bv[ni];
                const float qv = qrow[n0w + ni * 16 + l15];
                s2 += y * y; sd += y * qv;
            }
            #pragma unroll
            for (int off = 1; off < 16; off <<= 1) {
                s2 += __shfl_xor(s2, off);
                sd += __shfl_xor(sd, off);
            }
            if (l15 == 0) {
                atomicAdd(&kn2[mg], s2);
                atomicAdd(&dots[mg], sd);
            }
        }
}

// ---------------- single fused persistent kernel ----------------
__global__ __launch_bounds__(256, 4) void fused_kernel(
        const float* __restrict__ input, const float* __restrict__ kb,
        const float* __restrict__ W, const float* __restrict__ bias,
        float* __restrict__ out, char* __restrict__ ws) {
    __shared__ __align__(16) u16 As[128 * 32];
    __shared__ __align__(16) u16 Bs[128 * 32];

    u16*   Wb   = (u16*)(ws + WS_WBF);
    u16*   Aq   = (u16*)(ws + WS_AQ);
    float* q    = (float*)(ws + WS_Q);
    float* kn2  = (float*)(ws + WS_KN2);
    float* dots = (float*)(ws + WS_DOTS);
    u16*   Kbf  = (u16*)(ws + WS_KBF);
    u32*   bar  = (u32*)(ws + WS_BAR);

    const int tid = threadIdx.x;
    const int bid = blockIdx.x;
    const int gid = bid * NTHR + tid;          // 0..262143

    // ---- Phase A: W->bf16, input->Aq, q=bias, zero kn2/dots ----
    {
        const float4v* w4 = (const float4v*)W;
        u64* wd = (u64*)Wb;
        #pragma unroll
        for (int i = 0; i < 4; ++i) {
            const int idx = gid + i * (GRID * NTHR);
            wd[idx] = pack4(w4[idx]);
        }
        if (gid < 65536) {
            u64 v = 0;
            if (gid < 32768) v = pack4(((const float4v*)input)[gid]);
            ((u64*)Aq)[gid] = v;
        }
        if (gid < 32768)
            ((float4v*)q)[gid] = ((const float4v*)bias)[gid & 511];
        if (gid < 4096) ((float4v*)kn2)[gid] = float4v{0.f, 0.f, 0.f, 0.f};
        else if (gid < 8192) ((float4v*)dots)[gid - 4096] = float4v{0.f, 0.f, 0.f, 0.f};
    }
    gbar(bar + 0, GRID);

    // ---- Phase B: blocks 0-63 gemm0 (q += in@W^T) ; blocks 64+ convert kb->bf16 ----
    if (bid < 64) {
        gemm0_tile(Aq, Wb, q, As, Bs, bid & 15, bid >> 4);
    } else {
        const float4v* s4 = (const float4v*)kb;
        u64* d8 = (u64*)Kbf;
        for (int i = (bid - 64) * NTHR + tid; i < 8388608; i += (GRID - 64) * NTHR)
            d8[i] = pack4(s4[i]);
    }
    gbar(bar + 1, GRID);

    // ---- Phase C: big GEMM, 2048 tiles, fused norm/dot epilogue ----
    for (int x = bid; x < 2048; x += GRID)
        gemmC_tile(Kbf, Wb, bias, q, kn2, dots, As, Bs, x);
    gbar(bar + 2, GRID);

    // ---- Phase D+E fused: per-b softmax (redundant x4) + out = input + sum_k attn*kb ----
    if (bid < 256) {
        const int b = bid >> 2, hc = bid & 3;
        float* sm  = (float*)As;    // attn weights [256]
        float* buf = (float*)Bs;    // cross-wave reduce scratch [4]
        // qn
        float s = 0.f;
        #pragma unroll
        for (int i = 0; i < 8; ++i) {
            float v = q[b * H_DIM + i * 256 + tid];
            s += v * v;
        }
        #pragma unroll
        for (int o = 32; o >= 1; o >>= 1) s += __shfl_xor(s, o);
        if ((tid & 63) == 0) buf[tid >> 6] = s;
        __syncthreads();
        const float qn = fmaxf(sqrtf(buf[0] + buf[1] + buf[2] + buf[3]), 1e-8f);
        __syncthreads();
        // scores + softmax (k == tid)
        const float kn = fmaxf(sqrtf(kn2[tid * B_DIM + b]), 1e-8f);
        const float sc = dots[tid * B_DIM + b] / (qn * kn);
        float mx = sc;
        #pragma unroll
        for (int o = 32; o >= 1; o >>= 1) mx = fmaxf(mx, __shfl_xor(mx, o));
        if ((tid & 63) == 0) buf[tid >> 6] = mx;
        __syncthreads();
        mx = fmaxf(fmaxf(buf[0], buf[1]), fmaxf(buf[2], buf[3]));
        __syncthreads();
        const float e = expf(sc - mx);
        float se = e;
        #pragma unroll
        for (int o = 32; o >= 1; o >>= 1) se += __shfl_xor(se, o);
        if ((tid & 63) == 0) buf[tid >> 6] = se;
        __syncthreads();
        se = buf[0] + buf[1] + buf[2] + buf[3];
        sm[tid] = e / se;
        __syncthreads();
        // weighted sum over k for this block's 512-elem h-slice
        const u32* base = (const u32*)Kbf;
        const int h2 = hc * 512 + tid * 2;     // u32 units within the 1024-u32 row
        float s0 = 0.f, s1 = 0.f, s2 = 0.f, s3 = 0.f;
        #pragma unroll 8
        for (int k = 0; k < K_DIM; ++k) {
            const size_t off = (size_t)(k * B_DIM + b) * (H_DIM / 2) + h2;
            const u32 p0 = base[off], p1 = base[off + 1];
            const float a = sm[k];
            s0 += a * __uint_as_float(p0 << 16);
            s1 += a * __uint_as_float(p0 & 0xffff0000u);
            s2 += a * __uint_as_float(p1 << 16);
            s3 += a * __uint_as_float(p1 & 0xffff0000u);
        }
        const int h = h2 * 2;
        float4v iv = *(const float4v*)&input[(size_t)b * H_DIM + h];
        float4v r;
        r.x = iv.x + s0; r.y = iv.y + s1; r.z = iv.z + s2; r.w = iv.w + s3;
        *(float4v*)&out[(size_t)b * H_DIM + h] = r;
    }
}

extern "C" void kernel_launch(void* const* d_in, const int* in_sizes, int n_in,
                              void* d_out, int out_size, void* d_ws, size_t ws_size,
                              hipStream_t stream) {
    const float* input = (const float*)d_in[0];
    const float* kb    = (const float*)d_in[1];
    const float* W     = (const float*)d_in[2];
    const float* bias  = (const float*)d_in[3];
    float* out = (float*)d_out;
    char* ws = (char*)d_ws;

    hipMemsetAsync(ws + WS_BAR, 0, 64, stream);
    fused_kernel<<<GRID, NTHR, 0, stream>>>(input, kb, W, bias, out, ws);
}

// Round 6
// 400.627 us; speedup vs baseline: 2.7753x; 1.7556x over previous
//
#include <hip/hip_runtime.h>
#include <hip/hip_bf16.h>

typedef unsigned short u16;
typedef unsigned int u32;
typedef unsigned long long u64;
typedef __attribute__((ext_vector_type(8))) short short8;
typedef __attribute__((ext_vector_type(4))) float float4v;

#define B_DIM 64
#define H_DIM 2048
#define K_DIM 256
#define NTHR  256

// workspace layout (bytes)
#define WS_WBF   0ull                         // 2048*2048*2 = 8388608
#define WS_AQ    (8388608ull)                 // 128*2048*2  = 524288
#define WS_Q     (WS_AQ + 524288ull)          // 64*2048*4   = 524288
#define WS_KN2   (WS_Q + 524288ull)           // 16384*4
#define WS_DOTS  (WS_KN2 + 65536ull)          // 16384*4
#define WS_KBF   (WS_DOTS + 65536ull)         // 16384*2048*2 = 67108864

__device__ __forceinline__ u16 f2bf(float f) {
    unsigned int u = __float_as_uint(f);
    unsigned int r = (u + 0x7fffu + ((u >> 16) & 1u)) >> 16;
    return (u16)r;
}

__device__ __forceinline__ u64 pack4(float4v v) {
    u64 a0 = f2bf(v.x), a1 = f2bf(v.y), a2 = f2bf(v.z), a3 = f2bf(v.w);
    return a0 | (a1 << 16) | (a2 << 32) | (a3 << 48);
}

// async global->LDS 16B/lane; lds dest = wave-uniform base + lane*16
__device__ __forceinline__ void llds16(const u16* g, u16* l) {
    __builtin_amdgcn_global_load_lds(
        (__attribute__((address_space(1))) void*)g,
        (__attribute__((address_space(3))) void*)l, 16, 0, 0);
}

// ---- GEMM tile helpers. LDS XOR swizzle (proven in R5: SQ_LDS_BANK_CONFLICT=0):
// 16B granule g of row r is stored at slot g ^ ((r>>1)&3); staging lanes permute
// their global column within the same 64B segment so coalescing is unchanged.
__device__ __forceinline__ void gemm0_tile(const u16* __restrict__ Aq, const u16* __restrict__ Wb,
                                           float* __restrict__ qout, u16* As, u16* Bs,
                                           int nt, int ksplit) {
    const int tid = threadIdx.x;
    const int wave = tid >> 6, lane = tid & 63;
    const int l15 = lane & 15, qd = lane >> 4;
    const int wm = wave >> 1, wn = wave & 1;
    const int n0 = nt * 128;
    const int grow = lane >> 2;
    const int gcol = (((lane & 3) ^ ((lane >> 3) & 3)) * 8);
    const int sw = (l15 >> 1) & 3;
    float4v acc[4][4] = {};
    const int kb0 = ksplit * 512;
    for (int kk = 0; kk < 16; ++kk) {
        const int k0 = kb0 + kk * 32;
        #pragma unroll
        for (int i = 0; i < 2; ++i) {
            const int r = wave * 32 + i * 16;
            llds16(Wb + (size_t)(n0 + r + grow) * H_DIM + k0 + gcol, &Bs[r * 32]);
            llds16(Aq + (size_t)(r + grow) * H_DIM + k0 + gcol, &As[r * 32]);
        }
        __syncthreads();
        short8 af[4], bf_[4];
        #pragma unroll
        for (int mi = 0; mi < 4; ++mi)
            af[mi] = *(const short8*)&As[(wm * 64 + mi * 16 + l15) * 32 + ((qd ^ sw) * 8)];
        #pragma unroll
        for (int ni = 0; ni < 4; ++ni)
            bf_[ni] = *(const short8*)&Bs[(wn * 64 + ni * 16 + l15) * 32 + ((qd ^ sw) * 8)];
        #pragma unroll
        for (int mi = 0; mi < 4; ++mi)
            #pragma unroll
            for (int ni = 0; ni < 4; ++ni)
                acc[mi][ni] = __builtin_amdgcn_mfma_f32_16x16x32_bf16(af[mi], bf_[ni], acc[mi][ni], 0, 0, 0);
        __syncthreads();
    }
    const int n0w = n0 + wn * 64;
    if (wm == 0) {
        #pragma unroll
        for (int mi = 0; mi < 4; ++mi)
            #pragma unroll
            for (int reg = 0; reg < 4; ++reg) {
                const int m = mi * 16 + qd * 4 + reg;   // 0..63 == b
                #pragma unroll
                for (int ni = 0; ni < 4; ++ni)
                    atomicAdd(&qout[m * H_DIM + n0w + ni * 16 + l15], acc[mi][ni][reg]);
            }
    }
}

__device__ __forceinline__ void gemmC_tile(const u16* __restrict__ Kbf, const u16* __restrict__ Wb,
                                           const float* __restrict__ bias, const float* __restrict__ q,
                                           float* __restrict__ kn2, float* __restrict__ dots,
                                           u16* As, u16* Bs, int x) {
    const int tid = threadIdx.x;
    const int wave = tid >> 6, lane = tid & 63;
    const int l15 = lane & 15, qd = lane >> 4;
    const int wm = wave >> 1, wn = wave & 1;
    const int mt = (x >> 6) * 4 + (x & 3);     // L2-locality swizzle: 4 mt x 16 nt groups
    const int nt = (x >> 2) & 15;
    const int m0 = mt * 128, n0 = nt * 128;
    const int grow = lane >> 2;
    const int gcol = (((lane & 3) ^ ((lane >> 3) & 3)) * 8);
    const int sw = (l15 >> 1) & 3;
    float4v acc[4][4] = {};
    for (int kk = 0; kk < 64; ++kk) {
        const int k0 = kk * 32;
        #pragma unroll
        for (int i = 0; i < 2; ++i) {
            const int r = wave * 32 + i * 16;
            llds16(Wb + (size_t)(n0 + r + grow) * H_DIM + k0 + gcol, &Bs[r * 32]);
            llds16(Kbf + (size_t)(m0 + r + grow) * H_DIM + k0 + gcol, &As[r * 32]);
        }
        __syncthreads();
        short8 af[4], bf_[4];
        #pragma unroll
        for (int mi = 0; mi < 4; ++mi)
            af[mi] = *(const short8*)&As[(wm * 64 + mi * 16 + l15) * 32 + ((qd ^ sw) * 8)];
        #pragma unroll
        for (int ni = 0; ni < 4; ++ni)
            bf_[ni] = *(const short8*)&Bs[(wn * 64 + ni * 16 + l15) * 32 + ((qd ^ sw) * 8)];
        #pragma unroll
        for (int mi = 0; mi < 4; ++mi)
            #pragma unroll
            for (int ni = 0; ni < 4; ++ni)
                acc[mi][ni] = __builtin_amdgcn_mfma_f32_16x16x32_bf16(af[mi], bf_[ni], acc[mi][ni], 0, 0, 0);
        __syncthreads();
    }
    const int n0w = n0 + wn * 64;
    float bv[4];
    #pragma unroll
    for (int ni = 0; ni < 4; ++ni) bv[ni] = bias[n0w + ni * 16 + l15];
    #pragma unroll
    for (int mi = 0; mi < 4; ++mi)
        #pragma unroll
        for (int reg = 0; reg < 4; ++reg) {
            const int mloc = mi * 16 + qd * 4 + reg;     // b index
            const int mg = m0 + wm * 64 + mloc;
            const float* qrow = q + mloc * H_DIM;
            float s2 = 0.f, sd = 0.f;
            #pragma unroll
            for (int ni = 0; ni < 4; ++ni) {
                const float y = acc[mi][ni][reg] + bv[ni];
                const float qv = qrow[n0w + ni * 16 + l15];
                s2 += y * y; sd += y * qv;
            }
            #pragma unroll
            for (int off = 1; off < 16; off <<= 1) {
                s2 += __shfl_xor(s2, off);
                sd += __shfl_xor(sd, off);
            }
            if (l15 == 0) {
                atomicAdd(&kn2[mg], s2);
                atomicAdd(&dots[mg], sd);
            }
        }
}

// ---- k1: W->bf16 + input->Aq + q=bias + zero kn2/dots (grid 4096) ----
__global__ __launch_bounds__(256) void prep_kernel(
        const float* __restrict__ W, const float* __restrict__ input,
        const float* __restrict__ bias, u16* __restrict__ Wb,
        u16* __restrict__ Aq, float* __restrict__ q,
        float* __restrict__ kn2, float* __restrict__ dots) {
    const int gid = blockIdx.x * NTHR + threadIdx.x;   // 0..1048575
    ((u64*)Wb)[gid] = pack4(((const float4v*)W)[gid]);
    if (gid < 65536) {
        u64 v = 0;
        if (gid < 32768) v = pack4(((const float4v*)input)[gid]);
        ((u64*)Aq)[gid] = v;
    }
    if (gid < 32768)
        ((float4v*)q)[gid] = ((const float4v*)bias)[gid & 511];
    if (gid < 4096) ((float4v*)kn2)[gid] = float4v{0.f, 0.f, 0.f, 0.f};
    else if (gid < 8192) ((float4v*)dots)[gid - 4096] = float4v{0.f, 0.f, 0.f, 0.f};
}

// ---- k2: blocks 0-63 gemm0 (q += in@W^T, split-K atomics); blocks 64+ kb->bf16 ----
__global__ __launch_bounds__(256, 4) void mid_kernel(
        const float* __restrict__ kb, const u16* __restrict__ Aq,
        const u16* __restrict__ Wb, float* __restrict__ q, u16* __restrict__ Kbf) {
    __shared__ __align__(16) u16 As[128 * 32];
    __shared__ __align__(16) u16 Bs[128 * 32];
    const int bid = blockIdx.x;
    if (bid < 64) {
        gemm0_tile(Aq, Wb, q, As, Bs, bid & 15, bid >> 4);
    } else {
        const float4v* s4 = (const float4v*)kb;
        u64* d8 = (u64*)Kbf;
        for (int i = (bid - 64) * NTHR + threadIdx.x; i < 8388608; i += 960 * NTHR)
            d8[i] = pack4(s4[i]);
    }
}

// ---- k3: big GEMM (2048 tiles) with fused norm/dot epilogue ----
__global__ __launch_bounds__(256, 4) void gemm_kernel(
        const u16* __restrict__ Kbf, const u16* __restrict__ Wb,
        const float* __restrict__ bias, const float* __restrict__ q,
        float* __restrict__ kn2, float* __restrict__ dots) {
    __shared__ __align__(16) u16 As[128 * 32];
    __shared__ __align__(16) u16 Bs[128 * 32];
    gemmC_tile(Kbf, Wb, bias, q, kn2, dots, As, Bs, blockIdx.x);
}

// ---- k4: per-b softmax (recomputed per slice-block) + out = input + sum_k attn*kb ----
// grid 256: b = bid>>2, hc = bid&3; each thread handles ONE u32 (2 bf16) at
// h2 = hc*256+tid (0..1023) -> h = 2*h2 (in-bounds; fixes R4/R5 race+OOB).
__global__ __launch_bounds__(256) void final_kernel(
        const float* __restrict__ input, const u16* __restrict__ Kbf,
        const float* __restrict__ q, const float* __restrict__ kn2,
        const float* __restrict__ dots, float* __restrict__ out) {
    __shared__ float sm[K_DIM];
    __shared__ float buf[4];
    const int b = blockIdx.x >> 2, hc = blockIdx.x & 3, tid = threadIdx.x;
    // qn
    float s = 0.f;
    #pragma unroll
    for (int i = 0; i < 8; ++i) {
        float v = q[b * H_DIM + i * 256 + tid];
        s += v * v;
    }
    #pragma unroll
    for (int o = 32; o >= 1; o >>= 1) s += __shfl_xor(s, o);
    if ((tid & 63) == 0) buf[tid >> 6] = s;
    __syncthreads();
    const float qn = fmaxf(sqrtf(buf[0] + buf[1] + buf[2] + buf[3]), 1e-8f);
    __syncthreads();
    // score + softmax over k (k == tid)
    const float kn = fmaxf(sqrtf(kn2[tid * B_DIM + b]), 1e-8f);
    const float sc = dots[tid * B_DIM + b] / (qn * kn);
    float mx = sc;
    #pragma unroll
    for (int o = 32; o >= 1; o >>= 1) mx = fmaxf(mx, __shfl_xor(mx, o));
    if ((tid & 63) == 0) buf[tid >> 6] = mx;
    __syncthreads();
    mx = fmaxf(fmaxf(buf[0], buf[1]), fmaxf(buf[2], buf[3]));
    __syncthreads();
    const float e = expf(sc - mx);
    float se = e;
    #pragma unroll
    for (int o = 32; o >= 1; o >>= 1) se += __shfl_xor(se, o);
    if ((tid & 63) == 0) buf[tid >> 6] = se;
    __syncthreads();
    se = buf[0] + buf[1] + buf[2] + buf[3];
    sm[tid] = e / se;
    __syncthreads();
    // weighted sum for this block's 512-float h-slice
    const u32* base = (const u32*)Kbf;
    const int h2 = hc * 256 + tid;             // u32 unit, 0..1023
    float s0 = 0.f, s1 = 0.f;
    #pragma unroll 8
    for (int k = 0; k < K_DIM; ++k) {
        const u32 p = base[(size_t)(k * B_DIM + b) * (H_DIM / 2) + h2];
        const float a = sm[k];
        s0 += a * __uint_as_float(p << 16);
        s1 += a * __uint_as_float(p & 0xffff0000u);
    }
    const int h = h2 * 2;
    float2 iv = *(const float2*)&input[(size_t)b * H_DIM + h];
    float2 r; r.x = iv.x + s0; r.y = iv.y + s1;
    *(float2*)&out[(size_t)b * H_DIM + h] = r;
}

extern "C" void kernel_launch(void* const* d_in, const int* in_sizes, int n_in,
                              void* d_out, int out_size, void* d_ws, size_t ws_size,
                              hipStream_t stream) {
    const float* input = (const float*)d_in[0];
    const float* kb    = (const float*)d_in[1];
    const float* W     = (const float*)d_in[2];
    const float* bias  = (const float*)d_in[3];
    float* out = (float*)d_out;
    char* ws = (char*)d_ws;

    u16*   Wb   = (u16*)(ws + WS_WBF);
    u16*   Aq   = (u16*)(ws + WS_AQ);
    float* q    = (float*)(ws + WS_Q);
    float* kn2  = (float*)(ws + WS_KN2);
    float* dots = (float*)(ws + WS_DOTS);
    u16*   Kbf  = (u16*)(ws + WS_KBF);

    prep_kernel<<<4096, NTHR, 0, stream>>>(W, input, bias, Wb, Aq, q, kn2, dots);
    mid_kernel<<<1024, NTHR, 0, stream>>>(kb, Aq, Wb, q, Kbf);
    gemm_kernel<<<2048, NTHR, 0, stream>>>(Kbf, Wb, bias, q, kn2, dots);
    final_kernel<<<256, NTHR, 0, stream>>>(input, Kbf, q, kn2, dots, out);
}